// Round 8
// baseline (242.059 us; speedup 1.0000x reference)
//
#include <hip/hip_runtime.h>
#include <math.h>

#define Bb 4
#define Cc 256
#define Nn 4096
#define Dd 32
#define CH 128    // channels per attn block
#define NJ 32     // key tiles of 128
#define PST 136   // p_s row stride (shorts)
#define XST 264   // proj x-tile LDS row stride (shorts)

typedef __attribute__((ext_vector_type(8))) short bf16x8;
typedef __attribute__((ext_vector_type(4))) float f32x4;

union bfp { bf16x8 v; uint4 q; };

// pack two fp32 -> bf16x2 dword, round-half-up (perm + 2 adds)
__device__ __forceinline__ unsigned pk2r(float a, float b) {
    unsigned au = __builtin_bit_cast(unsigned, a) + 0x8000u;
    unsigned bu = __builtin_bit_cast(unsigned, b) + 0x8000u;
    return __builtin_amdgcn_perm(bu, au, 0x07060302u);
}
__device__ __forceinline__ void load_lds16(const void* g, void* l) {
    __builtin_amdgcn_global_load_lds(
        (const __attribute__((address_space(1))) void*)g,
        (__attribute__((address_space(3))) void*)l, 16, 0, 0);
}
__device__ __forceinline__ float fexp2(float x) {
#if __has_builtin(__builtin_amdgcn_exp2f)
    return __builtin_amdgcn_exp2f(x);
#else
    return __exp2f(x);
#endif
}
template <int CTRL>
__device__ __forceinline__ float dppf(float v) {
    int iv = __builtin_bit_cast(int, v);
    return __builtin_bit_cast(float,
        __builtin_amdgcn_update_dpp(iv, iv, CTRL, 0xF, 0xF, false));
}
__device__ __forceinline__ float rowsum16(float v) {
    v += dppf<0xB1>(v);
    v += dppf<0x4E>(v);
    v += dppf<0x141>(v);
    v += dppf<0x140>(v);
    return v;
}

// ---------------------------------------------------------------------------
// pack_w: W -> bf16 MFMA-fragment-major; Q rows pre-scaled log2e.
// ---------------------------------------------------------------------------
__global__ __launch_bounds__(256) void pack_w(
    const float* __restrict__ qw, const float* __restrict__ kw,
    const float* __restrict__ vw, short* __restrict__ wpk) {
    const int g = blockIdx.x * 256 + threadIdx.x;
    const int qd = g & 3, m = (g >> 2) & 15, kc = (g >> 6) & 7, ot = g >> 9;
    const int o = 16 * ot + m;
    const float* src; float sc = 1.0f;
    if (o < 32)      { src = qw + (size_t)o * Cc; sc = 1.44269504088896f; }
    else if (o < 64) { src = kw + (size_t)(o - 32) * Cc; }
    else             { src = vw + (size_t)(o - 64) * Cc; }
    const float* s8 = src + 32 * kc + 8 * qd;
    uint4 u;
    u.x = pk2r(s8[0] * sc, s8[1] * sc);
    u.y = pk2r(s8[2] * sc, s8[3] * sc);
    u.z = pk2r(s8[4] * sc, s8[5] * sc);
    u.w = pk2r(s8[6] * sc, s8[7] * sc);
    *(uint4*)(wpk + (size_t)g * 8) = u;
}

// ---------------------------------------------------------------------------
// proj: qkv = W x, bf16 MFMA, packed-W A-frags, LDS x^T staging.
// grid (128, 1, 4), 256 thr.
// ---------------------------------------------------------------------------
__global__ __launch_bounds__(256) void proj(
    const float* __restrict__ x, const short* __restrict__ wpk,
    short* __restrict__ q_t, short* __restrict__ k_t, short* __restrict__ v_b) {
    __shared__ alignas(16) short xs[32 * XST];
    const int b = blockIdx.z;
    const int n0 = blockIdx.x * 32;
    const int tid = threadIdx.x;
    const int w = tid >> 6;
    const int lane = tid & 63, qd = lane >> 4, m = lane & 15;

    {
        const int n = tid & 31, cgx = tid >> 5;
        const float* xp = x + ((size_t)b * Cc + 32 * cgx) * Nn + n0 + n;
        float xv[32];
#pragma unroll
        for (int i = 0; i < 32; ++i) xv[i] = xp[(size_t)i * Nn];
        short* row = xs + n * XST + 32 * cgx;
#pragma unroll
        for (int u4 = 0; u4 < 4; ++u4)
            *(uint4*)(row + 8 * u4) = make_uint4(
                pk2r(xv[8*u4+0], xv[8*u4+1]), pk2r(xv[8*u4+2], xv[8*u4+3]),
                pk2r(xv[8*u4+4], xv[8*u4+5]), pk2r(xv[8*u4+6], xv[8*u4+7]));
    }
    __syncthreads();

    const int fslot = m * 4 + qd;
    f32x4 acc[5][2];
#pragma unroll
    for (int i = 0; i < 5; ++i)
#pragma unroll
        for (int nt = 0; nt < 2; ++nt) acc[i][nt] = (f32x4){0.f, 0.f, 0.f, 0.f};

    bfp afc[5], afn[5];
#pragma unroll
    for (int i = 0; i < 5; ++i)
        afc[i].q = *(const uint4*)(wpk + ((size_t)((4*i + w) * 8) * 64 + fslot) * 8);

    for (int kc = 0; kc < 8; ++kc) {
        if (kc < 7) {
#pragma unroll
            for (int i = 0; i < 5; ++i)
                afn[i].q = *(const uint4*)(
                    wpk + ((size_t)((4*i + w) * 8 + kc + 1) * 64 + fslot) * 8);
        }
        bfp b0, b1;
        b0.q = *(const uint4*)&xs[(     m) * XST + 32 * kc + 8 * qd];
        b1.q = *(const uint4*)&xs[(16 + m) * XST + 32 * kc + 8 * qd];
#pragma unroll
        for (int i = 0; i < 5; ++i)
            acc[i][0] = __builtin_amdgcn_mfma_f32_16x16x32_bf16(afc[i].v, b0.v, acc[i][0], 0, 0, 0);
#pragma unroll
        for (int i = 0; i < 5; ++i)
            acc[i][1] = __builtin_amdgcn_mfma_f32_16x16x32_bf16(afc[i].v, b1.v, acc[i][1], 0, 0, 0);
#pragma unroll
        for (int i = 0; i < 5; ++i) afc[i] = afn[i];
    }

#pragma unroll
    for (int i = 0; i < 5; ++i) {
        const int ot = 4 * i + w;
        if (ot < 4) {
            short* dst = (ot < 2 ? q_t : k_t) + (size_t)b * Nn * Dd;
            const int dbase = (ot & 1) * 16 + 4 * qd;
#pragma unroll
            for (int nt = 0; nt < 2; ++nt) {
                const f32x4 a = acc[i][nt];
                *(uint2*)(dst + (size_t)(n0 + 16 * nt + m) * Dd + dbase) =
                    make_uint2(pk2r(a[0], a[1]), pk2r(a[2], a[3]));
            }
        } else {
            const int crow = (ot - 4) * 16 + 4 * qd;
            const int gbase = n0 & ~63;
            const int off2 = (n0 & 32) ? 2 : 0;
#pragma unroll
            for (int rr = 0; rr < 4; ++rr) {
                const unsigned pv = pk2r(acc[i][0][rr], acc[i][1][rr]);
                *(unsigned*)(v_b + ((size_t)b * Cc + crow + rr) * Nn +
                             gbase + 4 * m + off2) = pv;
            }
        }
    }
}

// ---------------------------------------------------------------------------
// attn: flash, bf16 MFMA, q-tile 32, grid 1024 = 4 blocks/CU (occupancy play).
//   S:  wave w -> m-tile (w&1), n-tiles of j-half (w>>1)   (4 MFMA, 4 K-frags)
//   PV: wave w -> c-quarter w, ALL j                       (16 MFMA, V in regs)
// P via LDS kappa-packed; no O reduction (wave owns c-quarter); l via DPP+LDS.
// LDS 25.3 KB.
// ---------------------------------------------------------------------------
__global__ __launch_bounds__(256, 4) void attn(
    const float* __restrict__ x, const short* __restrict__ q_t,
    const short* __restrict__ k_t, const short* __restrict__ v_b,
    const float* __restrict__ gamma, float* __restrict__ out) {
    __shared__ alignas(16) char pool[25344];
    short* k0s   = (short*)(pool);             // 8 KB  [j 0..127][d]
    short* k1s   = (short*)(pool + 8192);      // 8 KB
    short* p_s   = (short*)(pool + 16384);     // 32 x PST shorts, 8.7 KB
    float* l_red = (float*)(pool + 25088);     // [2][32]
    float* o_t   = (float*)(pool);             // epilogue overlay 32x132 f32

    const int bid = blockIdx.x;
    const int bcg = bid >> 7, it = bid & 127;
    const int b = bcg >> 1, cg = bcg & 1;
    const int i0 = it * 32;
    const int tid = threadIdx.x;
    const int w = tid >> 6, lane = tid & 63;
    const int qd = lane >> 4, m = lane & 15;
    const int mt = w & 1;      // S m-tile
    const int jg = w >> 1;     // S j-half

    const short* ktb = k_t + (size_t)b * Nn * Dd;
    const short* vtb = v_b + ((size_t)(b * Cc) + cg * CH) * Nn;

    // loop-invariant Q fragment (rows i0+16mt .. +15; pre-scaled by log2e)
    bfp af;
    af.q = *(const uint4*)(q_t + ((size_t)b * Nn + i0 + 16 * mt + m) * Dd + 8 * qd);

    // V row pointers: c = cg*CH + 32w + 16ct + m
    const short* vr[2];
#pragma unroll
    for (int ct = 0; ct < 2; ++ct)
        vr[ct] = vtb + (size_t)(32 * w + 16 * ct + m) * Nn + 8 * qd;

    // prologue: K tile 0 via DMA, V tile 0 -> regs
    load_lds16(ktb + tid * 8, k0s + tid * 8);
    load_lds16(ktb + 2048 + tid * 8, k0s + 2048 + tid * 8);
    uint4 va[8], vc[8];
#pragma unroll
    for (int ct = 0; ct < 2; ++ct)
#pragma unroll
        for (int kc = 0; kc < 4; ++kc)
            va[4 * ct + kc] = *(const uint4*)(vr[ct] + 32 * kc);

    f32x4 acc[2][2];
#pragma unroll
    for (int mtl = 0; mtl < 2; ++mtl)
#pragma unroll
        for (int ct = 0; ct < 2; ++ct) acc[mtl][ct] = (f32x4){0.f, 0.f, 0.f, 0.f};
    float lp[4] = {0.f, 0.f, 0.f, 0.f};

    auto body = [&](int jt, const short* kcur, short* knext,
                    uint4* vcur, uint4* vnext) {
        __syncthreads();   // B1: staging done; prior p_s reads done

        // ---- S: 1 m-tile x 4 n-tiles of this wave's j-half ----
        f32x4 sf[4];
#pragma unroll
        for (int ntl = 0; ntl < 4; ++ntl) {
            bfp kf;
            kf.q = *(const uint4*)(kcur + (64 * jg + 16 * ntl + m) * Dd + 8 * qd);
            sf[ntl] = __builtin_amdgcn_mfma_f32_16x16x32_bf16(
                af.v, kf.v, (f32x4){0.f, 0.f, 0.f, 0.f}, 0, 0, 0);
        }
        // ---- P = exp2(S'), l partials, packed kappa P write ----
#pragma unroll
        for (int rr = 0; rr < 4; ++rr) {
            const float p0 = fexp2(sf[0][rr]);
            const float p1 = fexp2(sf[1][rr]);
            const float p2 = fexp2(sf[2][rr]);
            const float p3 = fexp2(sf[3][rr]);
            lp[rr] += (p0 + p1) + (p2 + p3);
            const int row = 16 * mt + 4 * qd + rr;
            *(uint2*)&p_s[row * PST + 64 * jg + 4 * m] =
                make_uint2(pk2r(p0, p1), pk2r(p2, p3));
        }
        __syncthreads();   // B2: p_s visible

        // prefetch next K (LDS DMA) + next V (regs)
        if (jt + 1 < NJ) {
            const size_t ko = (size_t)(jt + 1) * 4096;
            load_lds16(ktb + ko + tid * 8, knext + tid * 8);
            load_lds16(ktb + ko + 2048 + tid * 8, knext + 2048 + tid * 8);
            const int joff = 128 * (jt + 1);
#pragma unroll
            for (int ct = 0; ct < 2; ++ct)
#pragma unroll
                for (int kc = 0; kc < 4; ++kc)
                    vnext[4 * ct + kc] = *(const uint4*)(vr[ct] + joff + 32 * kc);
        }
        // ---- PV: c-quarter w, all j ----
#pragma unroll
        for (int kc = 0; kc < 4; ++kc) {
            bf16x8 pa[2];
#pragma unroll
            for (int mtl = 0; mtl < 2; ++mtl) {
                bfp t;
                t.q = *(const uint4*)&p_s[(16 * mtl + m) * PST + 32 * kc + 8 * qd];
                pa[mtl] = t.v;
            }
#pragma unroll
            for (int ct = 0; ct < 2; ++ct) {
                bfp vv; vv.q = vcur[4 * ct + kc];
#pragma unroll
                for (int mtl = 0; mtl < 2; ++mtl)
                    acc[mtl][ct] = __builtin_amdgcn_mfma_f32_16x16x32_bf16(
                        pa[mtl], vv.v, acc[mtl][ct], 0, 0, 0);
            }
        }
    };

    for (int jt = 0; jt < NJ; jt += 2) {
        body(jt, k0s, k1s, va, vc);
        body(jt + 1, k1s, k0s, vc, va);
    }

    // ---- l: per-row DPP sums, publish per j-half ----
#pragma unroll
    for (int rr = 0; rr < 4; ++rr) {
        const float s = rowsum16(lp[rr]);
        if (m == 0) l_red[32 * jg + 16 * mt + 4 * qd + rr] = s;
    }

    // ---- epilogue: O transpose via LDS overlay; out = gamma*O/l + x ----
    __syncthreads();   // last PV p_s reads done; l_red written
#pragma unroll
    for (int mtl = 0; mtl < 2; ++mtl)
#pragma unroll
        for (int ct = 0; ct < 2; ++ct)
#pragma unroll
            for (int rr = 0; rr < 4; ++rr)
                o_t[(16 * mtl + 4 * qd + rr) * 132 + 32 * w + 16 * ct + m] =
                    acc[mtl][ct][rr];
    __syncthreads();

    const float gm = gamma[0];
    const int i = tid & 31, cch = tid >> 5;
    const float linv = 1.0f / (l_red[i] + l_red[32 + i]);
#pragma unroll
    for (int cc = 0; cc < 16; ++cc) {
        const int cl = cch * 16 + cc;
        const float val = o_t[i * 132 + cl] * linv;
        const size_t gidx = ((size_t)b * Cc + cg * CH + cl) * Nn + i0 + i;
        out[gidx] = gm * val + x[gidx];
    }
}

// ---------------------------------------------------------------------------
extern "C" void kernel_launch(void* const* d_in, const int* in_sizes, int n_in,
                              void* d_out, int out_size, void* d_ws, size_t ws_size,
                              hipStream_t stream) {
    const float* x     = (const float*)d_in[0];
    const float* qw    = (const float*)d_in[1];
    const float* kw    = (const float*)d_in[2];
    const float* vw    = (const float*)d_in[3];
    const float* gamma = (const float*)d_in[4];
    float* out = (float*)d_out;

    short* q_t = (short*)d_ws;                       // 1 MB   [b][n][32]
    short* k_t = q_t + (size_t)Bb * Nn * Dd;         // 1 MB   [b][n][32]
    short* v_b = k_t + (size_t)Bb * Nn * Dd;         // 8.4 MB [b][c][n~]
    short* wpk = v_b + (size_t)Bb * Cc * Nn;         // 160 KB packed W

    pack_w<<<dim3(40), 256, 0, stream>>>(qw, kw, vw, wpk);
    proj<<<dim3(Nn / 32, 1, Bb), 256, 0, stream>>>(x, wpk, q_t, k_t, v_b);
    attn<<<dim3(1024, 1, 1), 256, 0, stream>>>(x, q_t, k_t, v_b, gamma, out);
}

// Round 9
// 223.329 us; speedup vs baseline: 1.0839x; 1.0839x over previous
//
#include <hip/hip_runtime.h>
#include <math.h>

#define Bb 4
#define Cc 256
#define Nn 4096
#define Dd 32
#define CH 128    // channels per attn block
#define NJ 32     // key tiles of 128
#define PST 136   // p_s row stride (shorts)
#define XST 264   // proj x-tile LDS row stride (shorts)

typedef __attribute__((ext_vector_type(8))) short bf16x8;
typedef __attribute__((ext_vector_type(4))) float f32x4;

union bfp { bf16x8 v; uint4 q; };

// pack two fp32 -> bf16x2 dword, round-half-up (perm + 2 adds)
__device__ __forceinline__ unsigned pk2r(float a, float b) {
    unsigned au = __builtin_bit_cast(unsigned, a) + 0x8000u;
    unsigned bu = __builtin_bit_cast(unsigned, b) + 0x8000u;
    return __builtin_amdgcn_perm(bu, au, 0x07060302u);
}
__device__ __forceinline__ void load_lds16(const void* g, void* l) {
    __builtin_amdgcn_global_load_lds(
        (const __attribute__((address_space(1))) void*)g,
        (__attribute__((address_space(3))) void*)l, 16, 0, 0);
}
__device__ __forceinline__ float fexp2(float x) {
#if __has_builtin(__builtin_amdgcn_exp2f)
    return __builtin_amdgcn_exp2f(x);
#else
    return __exp2f(x);
#endif
}
template <int CTRL>
__device__ __forceinline__ float dppf(float v) {
    int iv = __builtin_bit_cast(int, v);
    return __builtin_bit_cast(float,
        __builtin_amdgcn_update_dpp(iv, iv, CTRL, 0xF, 0xF, false));
}
__device__ __forceinline__ float rowsum16(float v) {
    v += dppf<0xB1>(v);
    v += dppf<0x4E>(v);
    v += dppf<0x141>(v);
    v += dppf<0x140>(v);
    return v;
}

// ---------------------------------------------------------------------------
// pack_w: W -> bf16 MFMA-fragment-major; Q rows pre-scaled log2e.
// ---------------------------------------------------------------------------
__global__ __launch_bounds__(256) void pack_w(
    const float* __restrict__ qw, const float* __restrict__ kw,
    const float* __restrict__ vw, short* __restrict__ wpk) {
    const int g = blockIdx.x * 256 + threadIdx.x;
    const int qd = g & 3, m = (g >> 2) & 15, kc = (g >> 6) & 7, ot = g >> 9;
    const int o = 16 * ot + m;
    const float* src; float sc = 1.0f;
    if (o < 32)      { src = qw + (size_t)o * Cc; sc = 1.44269504088896f; }
    else if (o < 64) { src = kw + (size_t)(o - 32) * Cc; }
    else             { src = vw + (size_t)(o - 64) * Cc; }
    const float* s8 = src + 32 * kc + 8 * qd;
    uint4 u;
    u.x = pk2r(s8[0] * sc, s8[1] * sc);
    u.y = pk2r(s8[2] * sc, s8[3] * sc);
    u.z = pk2r(s8[4] * sc, s8[5] * sc);
    u.w = pk2r(s8[6] * sc, s8[7] * sc);
    *(uint4*)(wpk + (size_t)g * 8) = u;
}

// ---------------------------------------------------------------------------
// proj: qkv = W x, bf16 MFMA, packed-W A-frags, LDS x^T staging.
// grid (128, 1, 4), 256 thr.  (launched TWICE this round as a residue probe)
// ---------------------------------------------------------------------------
__global__ __launch_bounds__(256) void proj(
    const float* __restrict__ x, const short* __restrict__ wpk,
    short* __restrict__ q_t, short* __restrict__ k_t, short* __restrict__ v_b) {
    __shared__ alignas(16) short xs[32 * XST];
    const int b = blockIdx.z;
    const int n0 = blockIdx.x * 32;
    const int tid = threadIdx.x;
    const int w = tid >> 6;
    const int lane = tid & 63, qd = lane >> 4, m = lane & 15;

    {
        const int n = tid & 31, cgx = tid >> 5;
        const float* xp = x + ((size_t)b * Cc + 32 * cgx) * Nn + n0 + n;
        float xv[32];
#pragma unroll
        for (int i = 0; i < 32; ++i) xv[i] = xp[(size_t)i * Nn];
        short* row = xs + n * XST + 32 * cgx;
#pragma unroll
        for (int u4 = 0; u4 < 4; ++u4)
            *(uint4*)(row + 8 * u4) = make_uint4(
                pk2r(xv[8*u4+0], xv[8*u4+1]), pk2r(xv[8*u4+2], xv[8*u4+3]),
                pk2r(xv[8*u4+4], xv[8*u4+5]), pk2r(xv[8*u4+6], xv[8*u4+7]));
    }
    __syncthreads();

    const int fslot = m * 4 + qd;
    f32x4 acc[5][2];
#pragma unroll
    for (int i = 0; i < 5; ++i)
#pragma unroll
        for (int nt = 0; nt < 2; ++nt) acc[i][nt] = (f32x4){0.f, 0.f, 0.f, 0.f};

    bfp afc[5], afn[5];
#pragma unroll
    for (int i = 0; i < 5; ++i)
        afc[i].q = *(const uint4*)(wpk + ((size_t)((4*i + w) * 8) * 64 + fslot) * 8);

    for (int kc = 0; kc < 8; ++kc) {
        if (kc < 7) {
#pragma unroll
            for (int i = 0; i < 5; ++i)
                afn[i].q = *(const uint4*)(
                    wpk + ((size_t)((4*i + w) * 8 + kc + 1) * 64 + fslot) * 8);
        }
        bfp b0, b1;
        b0.q = *(const uint4*)&xs[(     m) * XST + 32 * kc + 8 * qd];
        b1.q = *(const uint4*)&xs[(16 + m) * XST + 32 * kc + 8 * qd];
#pragma unroll
        for (int i = 0; i < 5; ++i)
            acc[i][0] = __builtin_amdgcn_mfma_f32_16x16x32_bf16(afc[i].v, b0.v, acc[i][0], 0, 0, 0);
#pragma unroll
        for (int i = 0; i < 5; ++i)
            acc[i][1] = __builtin_amdgcn_mfma_f32_16x16x32_bf16(afc[i].v, b1.v, acc[i][1], 0, 0, 0);
#pragma unroll
        for (int i = 0; i < 5; ++i) afc[i] = afn[i];
    }

#pragma unroll
    for (int i = 0; i < 5; ++i) {
        const int ot = 4 * i + w;
        if (ot < 4) {
            short* dst = (ot < 2 ? q_t : k_t) + (size_t)b * Nn * Dd;
            const int dbase = (ot & 1) * 16 + 4 * qd;
#pragma unroll
            for (int nt = 0; nt < 2; ++nt) {
                const f32x4 a = acc[i][nt];
                *(uint2*)(dst + (size_t)(n0 + 16 * nt + m) * Dd + dbase) =
                    make_uint2(pk2r(a[0], a[1]), pk2r(a[2], a[3]));
            }
        } else {
            const int crow = (ot - 4) * 16 + 4 * qd;
            const int gbase = n0 & ~63;
            const int off2 = (n0 & 32) ? 2 : 0;
#pragma unroll
            for (int rr = 0; rr < 4; ++rr) {
                const unsigned pv = pk2r(acc[i][0][rr], acc[i][1][rr]);
                *(unsigned*)(v_b + ((size_t)b * Cc + crow + rr) * Nn +
                             gbase + 4 * m + off2) = pv;
            }
        }
    }
}

// ---------------------------------------------------------------------------
// attn: flash, bf16 MFMA, q-tile 32, grid 1024 = 4 blocks/CU.
//   S:  wave w -> m-tile (w&1) x j-half (w>>1)   (4 K-frags, 4 MFMA)
//   PV: wave w -> c-quarter w, all j; V loaded just-in-time from global (L2)
// No persistent V register buffers (R8's spill cause). bcg = bid&7 XCD swizzle.
// LDS 25.3 KB: K dbuf 16K + P 8.7K.
// ---------------------------------------------------------------------------
__global__ __launch_bounds__(256, 4) void attn(
    const float* __restrict__ x, const short* __restrict__ q_t,
    const short* __restrict__ k_t, const short* __restrict__ v_b,
    const float* __restrict__ gamma, float* __restrict__ out) {
    __shared__ alignas(16) char pool[25344];
    short* k0s   = (short*)(pool);             // 8 KB  [j 0..127][d]
    short* k1s   = (short*)(pool + 8192);      // 8 KB
    short* p_s   = (short*)(pool + 16384);     // 32 x PST shorts, 8.7 KB
    float* l_red = (float*)(pool + 25088);     // [2][32]
    float* o_t   = (float*)(pool);             // epilogue overlay 32x132 f32

    const int bid = blockIdx.x;
    const int bcg = bid & 7, it = bid >> 3;    // (b,cg) pinned per XCD slot
    const int b = bcg >> 1, cg = bcg & 1;
    const int i0 = it * 32;
    const int tid = threadIdx.x;
    const int w = tid >> 6, lane = tid & 63;
    const int qd = lane >> 4, m = lane & 15;
    const int mt = w & 1;      // S m-tile
    const int jg = w >> 1;     // S j-half

    const short* ktb = k_t + (size_t)b * Nn * Dd;
    const short* vtb = v_b + ((size_t)(b * Cc) + cg * CH) * Nn;

    // loop-invariant Q fragment (rows i0+16mt..+15; pre-scaled by log2e)
    bfp af;
    af.q = *(const uint4*)(q_t + ((size_t)b * Nn + i0 + 16 * mt + m) * Dd + 8 * qd);

    // V row pointers: c = cg*CH + 32w + 16ct + m  (kappa-ordered cols)
    const short* vr0 = vtb + (size_t)(32 * w + m) * Nn + 8 * qd;
    const short* vr1 = vtb + (size_t)(32 * w + 16 + m) * Nn + 8 * qd;

    // prologue: K tile 0 via DMA
    load_lds16(ktb + tid * 8, k0s + tid * 8);
    load_lds16(ktb + 2048 + tid * 8, k0s + 2048 + tid * 8);

    f32x4 acc[2][2];
#pragma unroll
    for (int mtl = 0; mtl < 2; ++mtl)
#pragma unroll
        for (int ct = 0; ct < 2; ++ct) acc[mtl][ct] = (f32x4){0.f, 0.f, 0.f, 0.f};
    float lp[4] = {0.f, 0.f, 0.f, 0.f};

    for (int jt = 0; jt < NJ; ++jt) {
        const short* kcur = (jt & 1) ? k1s : k0s;
        short*       knxt = (jt & 1) ? k0s : k1s;

        __syncthreads();   // B1: K staging arrived; prior p_s reads done

        // ---- S: 1 m-tile x 4 n-tiles of this wave's j-half ----
        f32x4 sf[4];
#pragma unroll
        for (int ntl = 0; ntl < 4; ++ntl) {
            bfp kf;
            kf.q = *(const uint4*)(kcur + (64 * jg + 16 * ntl + m) * Dd + 8 * qd);
            sf[ntl] = __builtin_amdgcn_mfma_f32_16x16x32_bf16(
                af.v, kf.v, (f32x4){0.f, 0.f, 0.f, 0.f}, 0, 0, 0);
        }
        // ---- P = exp2(S'), l partials, packed kappa P write ----
#pragma unroll
        for (int rr = 0; rr < 4; ++rr) {
            const float p0 = fexp2(sf[0][rr]);
            const float p1 = fexp2(sf[1][rr]);
            const float p2 = fexp2(sf[2][rr]);
            const float p3 = fexp2(sf[3][rr]);
            lp[rr] += (p0 + p1) + (p2 + p3);
            const int row = 16 * mt + 4 * qd + rr;
            *(uint2*)&p_s[row * PST + 64 * jg + 4 * m] =
                make_uint2(pk2r(p0, p1), pk2r(p2, p3));
        }
        __syncthreads();   // B2: p_s visible

        // prefetch next K tile (LDS DMA; drained at next B1)
        if (jt + 1 < NJ) {
            const size_t ko = (size_t)(jt + 1) * 4096;
            load_lds16(ktb + ko + tid * 8, knxt + tid * 8);
            load_lds16(ktb + ko + 2048 + tid * 8, knxt + 2048 + tid * 8);
        }

        // ---- PV: c-quarter w, all j; V just-in-time from global (L2) ----
        const int joff = 128 * jt;
        uint4 vld[8];
#pragma unroll
        for (int kc = 0; kc < 4; ++kc) {
            vld[kc]     = *(const uint4*)(vr0 + joff + 32 * kc);
            vld[4 + kc] = *(const uint4*)(vr1 + joff + 32 * kc);
        }
#pragma unroll
        for (int kc = 0; kc < 4; ++kc) {
            bfp pa0, pa1;
            pa0.q = *(const uint4*)&p_s[(     m) * PST + 32 * kc + 8 * qd];
            pa1.q = *(const uint4*)&p_s[(16 + m) * PST + 32 * kc + 8 * qd];
            bfp v0, v1;
            v0.q = vld[kc];
            v1.q = vld[4 + kc];
            acc[0][0] = __builtin_amdgcn_mfma_f32_16x16x32_bf16(pa0.v, v0.v, acc[0][0], 0, 0, 0);
            acc[1][0] = __builtin_amdgcn_mfma_f32_16x16x32_bf16(pa1.v, v0.v, acc[1][0], 0, 0, 0);
            acc[0][1] = __builtin_amdgcn_mfma_f32_16x16x32_bf16(pa0.v, v1.v, acc[0][1], 0, 0, 0);
            acc[1][1] = __builtin_amdgcn_mfma_f32_16x16x32_bf16(pa1.v, v1.v, acc[1][1], 0, 0, 0);
        }
    }

    // ---- l: per-row DPP sums, publish per j-half ----
#pragma unroll
    for (int rr = 0; rr < 4; ++rr) {
        const float s = rowsum16(lp[rr]);
        if (m == 0) l_red[32 * jg + 16 * mt + 4 * qd + rr] = s;
    }

    // ---- epilogue: O transpose via LDS overlay; out = gamma*O/l + x ----
    __syncthreads();   // last PV p_s reads done; l_red written
#pragma unroll
    for (int mtl = 0; mtl < 2; ++mtl)
#pragma unroll
        for (int ct = 0; ct < 2; ++ct)
#pragma unroll
            for (int rr = 0; rr < 4; ++rr)
                o_t[(16 * mtl + 4 * qd + rr) * 132 + 32 * w + 16 * ct + m] =
                    acc[mtl][ct][rr];
    __syncthreads();

    const float gm = gamma[0];
    const int i = tid & 31, cch = tid >> 5;
    const float linv = 1.0f / (l_red[i] + l_red[32 + i]);
#pragma unroll
    for (int cc = 0; cc < 16; ++cc) {
        const int cl = cch * 16 + cc;
        const float val = o_t[i * 132 + cl] * linv;
        const size_t gidx = ((size_t)b * Cc + cg * CH + cl) * Nn + i0 + i;
        out[gidx] = gm * val + x[gidx];
    }
}

// ---------------------------------------------------------------------------
extern "C" void kernel_launch(void* const* d_in, const int* in_sizes, int n_in,
                              void* d_out, int out_size, void* d_ws, size_t ws_size,
                              hipStream_t stream) {
    const float* x     = (const float*)d_in[0];
    const float* qw    = (const float*)d_in[1];
    const float* kw    = (const float*)d_in[2];
    const float* vw    = (const float*)d_in[3];
    const float* gamma = (const float*)d_in[4];
    float* out = (float*)d_out;

    short* q_t = (short*)d_ws;                       // 1 MB   [b][n][32]
    short* k_t = q_t + (size_t)Bb * Nn * Dd;         // 1 MB   [b][n][32]
    short* v_b = k_t + (size_t)Bb * Nn * Dd;         // 8.4 MB [b][c][n~]
    short* wpk = v_b + (size_t)Bb * Cc * Nn;         // 160 KB packed W

    pack_w<<<dim3(40), 256, 0, stream>>>(qw, kw, vw, wpk);
    // proj launched TWICE on purpose (idempotent): residue-composition probe.
    proj<<<dim3(Nn / 32, 1, Bb), 256, 0, stream>>>(x, wpk, q_t, k_t, v_b);
    proj<<<dim3(Nn / 32, 1, Bb), 256, 0, stream>>>(x, wpk, q_t, k_t, v_b);
    attn<<<dim3(1024, 1, 1), 256, 0, stream>>>(x, q_t, k_t, v_b, gamma, out);
}